// Round 2
// baseline (1986.568 us; speedup 1.0000x reference)
//
#include <hip/hip_runtime.h>
#include <cmath>

#define B_ 64
#define T_ 512
#define E_ 512
#define H_ 1024
#define O_ 512
#define BH (B_ * H_)
#define HSTRIDE 1160  // LDS row stride (elems): 2320B = 580 words, %32=4 -> 2-way max

typedef unsigned short ushort_t;
typedef __bf16 bf16x8 __attribute__((ext_vector_type(8)));
typedef float f32x4 __attribute__((ext_vector_type(4)));

__device__ __forceinline__ ushort_t f2bf(float f) {
    union { float f; unsigned int u; } x; x.f = f;
    unsigned int r = x.u + 0x7fffu + ((x.u >> 16) & 1u);
    return (ushort_t)(r >> 16);
}
__device__ __forceinline__ float bf2f(ushort_t u) {
    union { unsigned int u; float f; } x; x.u = ((unsigned int)u) << 16;
    return x.f;
}
__device__ __forceinline__ uint4 pack8bf(float4 v0, float4 v1) {
    uint4 pk;
    pk.x = (unsigned)f2bf(v0.x) | ((unsigned)f2bf(v0.y) << 16);
    pk.y = (unsigned)f2bf(v0.z) | ((unsigned)f2bf(v0.w) << 16);
    pk.z = (unsigned)f2bf(v1.x) | ((unsigned)f2bf(v1.y) << 16);
    pk.w = (unsigned)f2bf(v1.z) | ((unsigned)f2bf(v1.w) << 16);
    return pk;
}
__device__ __forceinline__ bf16x8 pack8(const float* src) {
    float4 v0 = *(const float4*)src;
    float4 v1 = *(const float4*)(src + 4);
    union { uint4 u; bf16x8 b; } c;
    c.u = pack8bf(v0, v1);
    return c.b;
}

// ---------------------------------------------------------------- prep ------
__global__ void prep_kernel(const float* __restrict__ h0, ushort_t* __restrict__ hinit,
                            int* __restrict__ bar) {
    int i = blockIdx.x * blockDim.x + threadIdx.x;
    if (i < 8192) bar[i] = 0;   // flag arrays: 4 groups x 32 flags x 32-int stride
    if (i < 2 * BH) hinit[i] = f2bf(h0[i]);
}

// ------------------------------------------------ big GEMM: C = A*W^T + b ---
// MODE 0: A fp32 (emb, (B,T,E), row r=t*64+b -> emb row (b,t)), out bf16 direct rows
// MODE 2: A bf16 direct rows, out fp32 remapped row r=t*64+b -> out row (b,t)
template <int MODE>
__launch_bounds__(256)
__global__ void gemm_bt(const void* __restrict__ Ap, const float* __restrict__ Wp,
                        const float* __restrict__ bias, void* __restrict__ outp,
                        int N, int K) {
    __shared__ __align__(16) ushort_t As[128 * 72];
    __shared__ __align__(16) ushort_t Bs[128 * 72];
    const int tid = threadIdx.x;
    const int lane = tid & 63;
    const int w = tid >> 6;
    const int wm = (w >> 1) * 64;
    const int wn = (w & 1) * 64;
    const int q = lane >> 4;
    const int l16 = lane & 15;
    const int m0 = blockIdx.y * 128;
    const int n0 = blockIdx.x * 128;

    const float*    Af = (const float*)Ap;
    const ushort_t* Ab = (const ushort_t*)Ap;

    f32x4 zero = {0.f, 0.f, 0.f, 0.f};
    f32x4 acc[4][4];
#pragma unroll
    for (int i = 0; i < 4; i++)
#pragma unroll
        for (int j = 0; j < 4; j++) acc[i][j] = zero;

    for (int k0 = 0; k0 < K; k0 += 64) {
#pragma unroll
        for (int it = 0; it < 4; it++) {
            int task = tid + it * 256;
            int row = task >> 3, seg = task & 7;
            if (MODE == 0) {
                int Ra = m0 + row;
                const float* src = Af + (size_t)((Ra & 63) * T_ + (Ra >> 6)) * K + k0 + seg * 8;
                float4 v0 = *(const float4*)src;
                float4 v1 = *(const float4*)(src + 4);
                *(uint4*)&As[row * 72 + seg * 8] = pack8bf(v0, v1);
            } else {
                const ushort_t* src = Ab + (size_t)(m0 + row) * K + k0 + seg * 8;
                *(uint4*)&As[row * 72 + seg * 8] = *(const uint4*)src;
            }
            const float* wsrc = Wp + (size_t)(n0 + row) * K + k0 + seg * 8;
            float4 w0 = *(const float4*)wsrc;
            float4 w1 = *(const float4*)(wsrc + 4);
            *(uint4*)&Bs[row * 72 + seg * 8] = pack8bf(w0, w1);
        }
        __syncthreads();
#pragma unroll
        for (int ks = 0; ks < 64; ks += 32) {
            bf16x8 af[4], bfr[4];
#pragma unroll
            for (int i = 0; i < 4; i++)
                af[i] = *(const bf16x8*)&As[(wm + i * 16 + l16) * 72 + ks + q * 8];
#pragma unroll
            for (int j = 0; j < 4; j++)
                bfr[j] = *(const bf16x8*)&Bs[(wn + j * 16 + l16) * 72 + ks + q * 8];
#pragma unroll
            for (int i = 0; i < 4; i++)
#pragma unroll
                for (int j = 0; j < 4; j++)
                    acc[i][j] = __builtin_amdgcn_mfma_f32_16x16x32_bf16(af[i], bfr[j], acc[i][j], 0, 0, 0);
        }
        __syncthreads();
    }

#pragma unroll
    for (int j = 0; j < 4; j++) {
        int C = n0 + wn + j * 16 + l16;
        float bv = bias[C];
#pragma unroll
        for (int i = 0; i < 4; i++) {
#pragma unroll
            for (int r = 0; r < 4; r++) {
                int R = m0 + wm + i * 16 + q * 4 + r;
                float v = acc[i][j][r] + bv;
                if (MODE == 2) {
                    ((float*)outp)[(size_t)((R & 63) * T_ + (R >> 6)) * N + C] = v;
                } else {
                    ((ushort_t*)outp)[(size_t)R * N + C] = f2bf(v);
                }
            }
        }
    }
}

// ---------------- merged two-layer persistent recurrence (single chain) -----
// 128 blocks x 256 threads, 1 block/CU. Block (gb, cb): batch rows [16gb,+16),
// cols [32cb,+32) of BOTH h0 and h1. Round k (k=0..512):
//   poll flags >= k  (round k-1 publishes visible)
//   load A = h0(k-1) (16x1024) and B = h1(k-2) (16x1024), coherent
//   h0(k)   = tanh(xw(k) + A.W_hh0^T + b)          [k <= 511]
//   h1(k-1) = tanh(A.W_ih1^T + B.W_hh1^T + b)      [k >= 1]
//   publish both (coherent stores), one drain, flag = k+1
// A serves both layers (layer-1's x-input IS h0) -> one sync chain total.
// Flags: bar + gb*1024, 32 flags @ 128B stride, monotonic.
__launch_bounds__(256, 1)
__global__ void rnn_merged(ushort_t* __restrict__ x0,      // (T,B,H) bf16, in: xp, out: h0
                           ushort_t* __restrict__ x1,      // (T,B,H) bf16, out: h1
                           const ushort_t* __restrict__ hinit,  // 2 x (B,H) bf16
                           const float* __restrict__ W_hh0, const float* __restrict__ b_hh0,
                           const float* __restrict__ W_ih1, const float* __restrict__ W_hh1,
                           const float* __restrict__ b_ih1, const float* __restrict__ b_hh1,
                           int* __restrict__ bar) {
    __shared__ __align__(16) ushort_t Hs0[16 * HSTRIDE];  // A = h0(k-1)
    __shared__ __align__(16) ushort_t Hs1[16 * HSTRIDE];  // B = h1(k-2)
    __shared__ float Rs0[4][16][33];                      // layer-0 partials
    __shared__ float Rs1[4][16][33];                      // layer-1 partials

    const int tid = threadIdx.x;
    const int lane = tid & 63;
    const int w = tid >> 6;
    const int q = lane >> 4;
    const int l16 = lane & 15;
    const int gb = blockIdx.x >> 5;       // 4 batch groups x 32 col blocks
    const int cb = blockIdx.x & 31;
    const int b0 = gb * 16;
    const int n0 = cb * 32;
    int* flags  = bar + gb * 1024;
    int* pollp  = flags + ((lane & 31) << 5);
    int* myflag = flags + (cb << 5);

    // ---- register B-fragments (loop-invariant weights: 3 matrices x 32 cols)
    bf16x8 w0[16], wI[16], wH[16];
#pragma unroll
    for (int g = 0; g < 2; g++)
#pragma unroll
        for (int kk = 0; kk < 8; kk++) {
            size_t off = (size_t)(n0 + g * 16 + l16) * H_ + w * 256 + kk * 32 + q * 8;
            w0[g * 8 + kk] = pack8(W_hh0 + off);
            wI[g * 8 + kk] = pack8(W_ih1 + off);
            wH[g * 8 + kk] = pack8(W_hh1 + off);
        }

    const int em = tid >> 4;        // 0..15 row
    const int en = (tid & 15) * 2;  // col pair within 32
    const float bv00 = b_hh0[n0 + en],     bv01 = b_hh0[n0 + en + 1];
    const float bv10 = b_ih1[n0 + en] + b_hh1[n0 + en];
    const float bv11 = b_ih1[n0 + en + 1] + b_hh1[n0 + en + 1];

    const int rbase2 = (tid >> 7) * 2;  // 0 or 2
    const int seg = tid & 127;
    const ushort_t* hinit0 = hinit;
    const ushort_t* hinit1 = hinit + BH;

    for (int k = 0; k < 513; k++) {
        // ---- flag-array barrier wait: all 32 producer flags >= k
        if (k > 0) {
            while (true) {
                int v = __hip_atomic_load(pollp, __ATOMIC_RELAXED, __HIP_MEMORY_SCOPE_SYSTEM);
                if (__ballot(v >= k) == ~0ull) break;
            }
        }

        // ---- coherent loads: A = h0(k-1), B = h1(k-2), + xw = xp(k) own word
        const ushort_t* Asrc = (k == 0) ? hinit0 : (x0 + (size_t)(k - 1) * BH);
        const ushort_t* Bsrc = (k <= 1) ? hinit1 : (x1 + (size_t)(k - 2) * BH);
        const ushort_t* a0 = Asrc + (size_t)(b0 + rbase2) * H_ + seg * 8;
        const ushort_t* a1 = a0 + 4 * H_;
        const ushort_t* a2 = a0 + 8 * H_;
        const ushort_t* a3 = a0 + 12 * H_;
        const ushort_t* c0 = Bsrc + (size_t)(b0 + rbase2) * H_ + seg * 8;
        const ushort_t* c1 = c0 + 4 * H_;
        const ushort_t* c2 = c0 + 8 * H_;
        const ushort_t* c3 = c0 + 12 * H_;
        const int kc = (k <= 511) ? k : 511;  // clamp xw addr (value unused at k=512)
        const ushort_t* xaddr = x0 + (size_t)kc * BH + (size_t)(b0 + em) * H_ + n0 + en;
        uint4 A0, A1, A2, A3, A4, A5, A6, A7;
        uint4 B0, B1, B2, B3, B4, B5, B6, B7;
        unsigned xw;
        asm volatile(
            "global_load_dwordx4 %0, %17, off sc0 sc1\n\t"
            "global_load_dwordx4 %1, %17, off offset:2048 sc0 sc1\n\t"
            "global_load_dwordx4 %2, %18, off sc0 sc1\n\t"
            "global_load_dwordx4 %3, %18, off offset:2048 sc0 sc1\n\t"
            "global_load_dwordx4 %4, %19, off sc0 sc1\n\t"
            "global_load_dwordx4 %5, %19, off offset:2048 sc0 sc1\n\t"
            "global_load_dwordx4 %6, %20, off sc0 sc1\n\t"
            "global_load_dwordx4 %7, %20, off offset:2048 sc0 sc1\n\t"
            "global_load_dwordx4 %8, %21, off sc0 sc1\n\t"
            "global_load_dwordx4 %9, %21, off offset:2048 sc0 sc1\n\t"
            "global_load_dwordx4 %10, %22, off sc0 sc1\n\t"
            "global_load_dwordx4 %11, %22, off offset:2048 sc0 sc1\n\t"
            "global_load_dwordx4 %12, %23, off sc0 sc1\n\t"
            "global_load_dwordx4 %13, %23, off offset:2048 sc0 sc1\n\t"
            "global_load_dwordx4 %14, %24, off sc0 sc1\n\t"
            "global_load_dwordx4 %15, %24, off offset:2048 sc0 sc1\n\t"
            "global_load_dword %16, %25, off sc0 sc1\n\t"
            "s_waitcnt vmcnt(0)"
            : "=&v"(A0), "=&v"(A1), "=&v"(A2), "=&v"(A3),
              "=&v"(A4), "=&v"(A5), "=&v"(A6), "=&v"(A7),
              "=&v"(B0), "=&v"(B1), "=&v"(B2), "=&v"(B3),
              "=&v"(B4), "=&v"(B5), "=&v"(B6), "=&v"(B7), "=&v"(xw)
            : "v"(a0), "v"(a1), "v"(a2), "v"(a3),
              "v"(c0), "v"(c1), "v"(c2), "v"(c3), "v"(xaddr)
            : "memory");

        *(uint4*)&Hs0[(rbase2 + 0) * HSTRIDE + seg * 8] = A0;
        *(uint4*)&Hs0[(rbase2 + 1) * HSTRIDE + seg * 8] = A1;
        *(uint4*)&Hs0[(rbase2 + 4) * HSTRIDE + seg * 8] = A2;
        *(uint4*)&Hs0[(rbase2 + 5) * HSTRIDE + seg * 8] = A3;
        *(uint4*)&Hs0[(rbase2 + 8) * HSTRIDE + seg * 8] = A4;
        *(uint4*)&Hs0[(rbase2 + 9) * HSTRIDE + seg * 8] = A5;
        *(uint4*)&Hs0[(rbase2 + 12) * HSTRIDE + seg * 8] = A6;
        *(uint4*)&Hs0[(rbase2 + 13) * HSTRIDE + seg * 8] = A7;
        *(uint4*)&Hs1[(rbase2 + 0) * HSTRIDE + seg * 8] = B0;
        *(uint4*)&Hs1[(rbase2 + 1) * HSTRIDE + seg * 8] = B1;
        *(uint4*)&Hs1[(rbase2 + 4) * HSTRIDE + seg * 8] = B2;
        *(uint4*)&Hs1[(rbase2 + 5) * HSTRIDE + seg * 8] = B3;
        *(uint4*)&Hs1[(rbase2 + 8) * HSTRIDE + seg * 8] = B4;
        *(uint4*)&Hs1[(rbase2 + 9) * HSTRIDE + seg * 8] = B5;
        *(uint4*)&Hs1[(rbase2 + 12) * HSTRIDE + seg * 8] = B6;
        *(uint4*)&Hs1[(rbase2 + 13) * HSTRIDE + seg * 8] = B7;
        __syncthreads();

        // ---- MFMA: wave w covers K slice [256w,+256). A-frag feeds 4 MFMAs
        // (layer-0 W_hh0 x2 col groups + layer-1 W_ih1 x2); B-frag feeds 2.
        f32x4 z = {0.f, 0.f, 0.f, 0.f};
        f32x4 a00 = z, a01 = z, a10 = z, a11 = z;
        const int kb = w * 256;
#pragma unroll
        for (int kk = 0; kk < 8; kk++) {
            bf16x8 a = *(const bf16x8*)&Hs0[l16 * HSTRIDE + kb + kk * 32 + q * 8];
            a00 = __builtin_amdgcn_mfma_f32_16x16x32_bf16(a, w0[kk], a00, 0, 0, 0);
            a01 = __builtin_amdgcn_mfma_f32_16x16x32_bf16(a, w0[8 + kk], a01, 0, 0, 0);
            a10 = __builtin_amdgcn_mfma_f32_16x16x32_bf16(a, wI[kk], a10, 0, 0, 0);
            a11 = __builtin_amdgcn_mfma_f32_16x16x32_bf16(a, wI[8 + kk], a11, 0, 0, 0);
        }
#pragma unroll
        for (int kk = 0; kk < 8; kk++) {
            bf16x8 b = *(const bf16x8*)&Hs1[l16 * HSTRIDE + kb + kk * 32 + q * 8];
            a10 = __builtin_amdgcn_mfma_f32_16x16x32_bf16(b, wH[kk], a10, 0, 0, 0);
            a11 = __builtin_amdgcn_mfma_f32_16x16x32_bf16(b, wH[8 + kk], a11, 0, 0, 0);
        }
#pragma unroll
        for (int rr = 0; rr < 4; rr++) {
            Rs0[w][q * 4 + rr][l16] = a00[rr];
            Rs0[w][q * 4 + rr][16 + l16] = a01[rr];
            Rs1[w][q * 4 + rr][l16] = a10[rr];
            Rs1[w][q * 4 + rr][16 + l16] = a11[rr];
        }
        __syncthreads();

        // ---- reduce 4 waves + tanh + coherent store (both layers)
        if (k <= 511) {
            float sA = Rs0[0][em][en] + Rs0[1][em][en] + Rs0[2][em][en] + Rs0[3][em][en];
            float sB = Rs0[0][em][en + 1] + Rs0[1][em][en + 1] + Rs0[2][em][en + 1] + Rs0[3][em][en + 1];
            sA += bf2f((ushort_t)(xw & 0xffff)) + bv00;
            sB += bf2f((ushort_t)(xw >> 16)) + bv01;
            unsigned pk = (unsigned)f2bf(tanhf(sA)) | ((unsigned)f2bf(tanhf(sB)) << 16);
            ushort_t* dst = x0 + (size_t)k * BH + (size_t)(b0 + em) * H_ + n0 + en;
            __hip_atomic_store((unsigned*)dst, pk, __ATOMIC_RELAXED, __HIP_MEMORY_SCOPE_SYSTEM);
        }
        if (k >= 1) {
            float sA = Rs1[0][em][en] + Rs1[1][em][en] + Rs1[2][em][en] + Rs1[3][em][en];
            float sB = Rs1[0][em][en + 1] + Rs1[1][em][en + 1] + Rs1[2][em][en + 1] + Rs1[3][em][en + 1];
            sA += bv10;
            sB += bv11;
            unsigned pk = (unsigned)f2bf(tanhf(sA)) | ((unsigned)f2bf(tanhf(sB)) << 16);
            ushort_t* dst = x1 + (size_t)(k - 1) * BH + (size_t)(b0 + em) * H_ + n0 + en;
            __hip_atomic_store((unsigned*)dst, pk, __ATOMIC_RELAXED, __HIP_MEMORY_SCOPE_SYSTEM);
        }

        // ---- signal: drain stores (syncthreads implies vmcnt(0)), publish flag
        if (k < 512) {
            __syncthreads();
            if (tid == 0)
                __hip_atomic_store(myflag, k + 1, __ATOMIC_RELAXED, __HIP_MEMORY_SCOPE_SYSTEM);
        }
    }
}

// ---------------------------------------------------------------- launch ----
extern "C" void kernel_launch(void* const* d_in, const int* in_sizes, int n_in,
                              void* d_out, int out_size, void* d_ws, size_t ws_size,
                              hipStream_t stream) {
    (void)in_sizes; (void)n_in; (void)out_size; (void)ws_size;
    const float* emb   = (const float*)d_in[0];
    const float* h0    = (const float*)d_in[1];
    const float* W_ih0 = (const float*)d_in[2];
    const float* b_ih0 = (const float*)d_in[3];
    const float* W_ih1 = (const float*)d_in[4];
    const float* b_ih1 = (const float*)d_in[5];
    const float* W_hh0 = (const float*)d_in[6];
    const float* b_hh0 = (const float*)d_in[7];
    const float* W_hh1 = (const float*)d_in[8];
    const float* b_hh1 = (const float*)d_in[9];
    const float* W_out = (const float*)d_in[10];
    const float* b_out = (const float*)d_in[11];
    float* out = (float*)d_out;

    char* ws = (char*)d_ws;
    int*      bar   = (int*)ws;                      // flag arrays (4096 ints used)
    ushort_t* hinit = (ushort_t*)(ws + 65536);       // 2*B*H bf16
    ushort_t* xp    = (ushort_t*)(ws + 65536 + 2 * BH * 2);  // (T,B,H) bf16: x0 -> h0
    ushort_t* xq    = xp + (size_t)T_ * BH;                  // (T,B,H) bf16: h1

    prep_kernel<<<512, 256, 0, stream>>>(h0, hinit, bar);

    // xp = emb . W_ih0^T + b_ih0   (stored (T,B,H))
    gemm_bt<0><<<dim3(H_ / 128, (B_ * T_) / 128), 256, 0, stream>>>(
        emb, W_ih0, b_ih0, xp, H_, E_);

    // merged recurrence: both layers, single sync chain
    rnn_merged<<<128, 256, 0, stream>>>(xp, xq, hinit,
                                        W_hh0, b_hh0, W_ih1, W_hh1, b_ih1, b_hh1, bar);

    // out = h1_all . W_out^T + b_out   ((B,T,O) fp32)
    gemm_bt<2><<<dim3(O_ / 128, (B_ * T_) / 128), 256, 0, stream>>>(
        xq, W_out, b_out, out, O_, H_);
}